// Round 6
// baseline (2566.854 us; speedup 1.0000x reference)
//
#include <hip/hip_runtime.h>
#include <math.h>

#define BATCH 256
#define NH 512
#define NCOND 1024
#define NV 32002
#define NT 15
#define NVT_F32 501   // fallback fp32 path
#define NBLK 502      // cooperative grid

// splitter section sizes in float4 units
#define SP_P  4096256   // NV*NH/4
#define SP_IH 196608
#define SP_HH 196608
#define SP_C  131072
#define SP_SMALL (SP_IH+SP_HH+SP_C)   // 524288
#define WP_A  2457600                 // Wp split part A (f4 elems), rest in part B

typedef short short8 __attribute__((ext_vector_type(8)));
typedef float float4v __attribute__((ext_vector_type(4)));

__device__ __forceinline__ void async_load16(const void* g, void* l){
  __builtin_amdgcn_global_load_lds(
      (const __attribute__((address_space(1))) void*)g,
      (__attribute__((address_space(3))) void*)l, 16, 0, 0);
}

__device__ __forceinline__ void split2(float x, unsigned short& hi, unsigned short& lo){
  unsigned u = __float_as_uint(x);
  unsigned r = u + 0x7fffu + ((u >> 16) & 1u);
  hi = (unsigned short)(r >> 16);
  float fh = __uint_as_float(r & 0xffff0000u);
  float res = x - fh;
  unsigned u2 = __float_as_uint(res);
  unsigned r2 = u2 + 0x7fffu + ((u2 >> 16) & 1u);
  lo = (unsigned short)(r2 >> 16);
}

__device__ __forceinline__ unsigned long long pack_key(float v, int idx){
  unsigned u = __float_as_uint(v);
  u = (u & 0x80000000u) ? ~u : (u | 0x80000000u);
  return ((unsigned long long)u << 32) | (unsigned)(0x7fffffff - idx);
}
__device__ __forceinline__ int key_tok(unsigned long long k){
  return 0x7fffffff - (int)(unsigned)(k & 0xffffffffu);
}

// device-scope grid barrier (cooperative launch => all blocks resident)
__device__ __forceinline__ void gbar(unsigned* cnt, unsigned& target){
  __syncthreads();
  if (threadIdx.x == 0){
    target += NBLK;
    __hip_atomic_fetch_add(cnt, 1u, __ATOMIC_ACQ_REL, __HIP_MEMORY_SCOPE_AGENT);
    while (__hip_atomic_load(cnt, __ATOMIC_ACQUIRE, __HIP_MEMORY_SCOPE_AGENT) < target)
      __builtin_amdgcn_s_sleep(16);
  }
  __syncthreads();
}

// ---------------- split helpers ----------------
__device__ __forceinline__ void split_elem(const float* __restrict__ src,
    unsigned short* __restrict__ dh, unsigned short* __restrict__ dl, size_t i){
  float4 v = *(const float4*)(src + i*4);
  unsigned short h0,l0,h1,l1,h2,l2,h3,l3;
  split2(v.x,h0,l0); split2(v.y,h1,l1); split2(v.z,h2,l2); split2(v.w,h3,l3);
  ushort4 hs = {h0,h1,h2,h3};
  ushort4 ls = {l0,l1,l2,l3};
  *(ushort4*)(dh + i*4) = hs;
  *(ushort4*)(dl + i*4) = ls;
}

__device__ __forceinline__ void split_small_elem(size_t i,
    const float* wih, const float* whh, const float* Wc,
    unsigned short* W6hi, unsigned short* W6lo,
    unsigned short* Wchi, unsigned short* Wclo){
  if (i < SP_IH) split_elem(wih, W6hi, W6lo, i);
  else if (i < SP_IH + SP_HH) split_elem(whh, W6hi + 786432, W6lo + 786432, i - SP_IH);
  else split_elem(Wc, Wchi, Wclo, i - SP_IH - SP_HH);
}

// ---------------- phase: h0 = img @ W_cond^T + b_cond ----------------
// blk 0..127: 16j x 64b, K=1024, BK=64. smem use: 20480 B
__device__ __forceinline__ void phase_h0(char* smem, int blk,
    const float* __restrict__ img,
    const unsigned short* __restrict__ Wchi, const unsigned short* __restrict__ Wclo,
    const float* __restrict__ bc,
    float* __restrict__ h0,
    unsigned short* __restrict__ hhi, unsigned short* __restrict__ hlo){
  char* hA = smem;          // [2][2048]
  char* hB = smem + 4096;   // [2][8192]
  int tid = threadIdx.x, w = tid >> 6, lane = tid & 63;
  int jbase = (blk & 31) * 16, bbase = (blk >> 5) * 64;
  int r16 = lane & 15, q = lane >> 4;
  float4v acc = {0.f,0.f,0.f,0.f};
  for (int k0 = 0; k0 < NCOND; k0 += 64){
    { int arr = w >> 1, t = w & 1;
      int a = t*8 + (lane >> 3);
      int p = (lane & 7) ^ ((lane >> 3) & 7);
      const unsigned short* gs = (arr ? Wclo : Wchi) + (size_t)(jbase + a)*NCOND + k0 + p*8;
      async_load16(gs, hA + arr*2048 + t*1024);
    }
    #pragma unroll
    for (int i = 0; i < 2; i++){
      int u = tid + 256*i;
      int b = u >> 3, s = u & 7;
      int p = s ^ (b & 7);
      const float* gp = img + (size_t)(bbase + b)*NCOND + k0 + p*8;
      float4 f0 = *(const float4*)gp, f1 = *(const float4*)(gp + 4);
      short8 hv, lv; unsigned short hh, ll;
      split2(f0.x,hh,ll); hv[0]=(short)hh; lv[0]=(short)ll;
      split2(f0.y,hh,ll); hv[1]=(short)hh; lv[1]=(short)ll;
      split2(f0.z,hh,ll); hv[2]=(short)hh; lv[2]=(short)ll;
      split2(f0.w,hh,ll); hv[3]=(short)hh; lv[3]=(short)ll;
      split2(f1.x,hh,ll); hv[4]=(short)hh; lv[4]=(short)ll;
      split2(f1.y,hh,ll); hv[5]=(short)hh; lv[5]=(short)ll;
      split2(f1.z,hh,ll); hv[6]=(short)hh; lv[6]=(short)ll;
      split2(f1.w,hh,ll); hv[7]=(short)hh; lv[7]=(short)ll;
      *(short8*)(hB + b*128 + s*16) = hv;
      *(short8*)(hB + 8192 + b*128 + s*16) = lv;
    }
    __syncthreads();
    int rb = w*16 + r16;
    #pragma unroll
    for (int kh = 0; kh < 2; kh++){
      int pa = kh*4 + q;
      int offA = r16*128 + ((pa ^ (r16 & 7))*16);
      int offB = rb*128 + ((pa ^ (rb & 7))*16);
      short8 ah = *(const short8*)(hA + offA);
      short8 al = *(const short8*)(hA + 2048 + offA);
      short8 bh = *(const short8*)(hB + offB);
      short8 bl = *(const short8*)(hB + 8192 + offB);
      acc = __builtin_amdgcn_mfma_f32_16x16x32_bf16(ah, bh, acc, 0,0,0);
      acc = __builtin_amdgcn_mfma_f32_16x16x32_bf16(ah, bl, acc, 0,0,0);
      acc = __builtin_amdgcn_mfma_f32_16x16x32_bf16(al, bh, acc, 0,0,0);
    }
    __syncthreads();
  }
  int b = bbase + w*16 + r16;
  #pragma unroll
  for (int reg = 0; reg < 4; reg++){
    int j = jbase + q*4 + reg;
    float val = acc[reg] + bc[j];
    h0[(size_t)b*NH + j] = val;
    unsigned short sh, sl; split2(val, sh, sl);
    hhi[(size_t)b*NH + j] = sh;
    hlo[(size_t)b*NH + j] = sl;
  }
}

// ---------------- phase: GRU step (blk 0..255: 16j x 32b, BK=64) ----------------
// smem use: 47232 B
__device__ __forceinline__ void phase_gru(char* smem, int blk,
    const int* __restrict__ cap, const unsigned long long* __restrict__ slot_prev,
    const float* __restrict__ emb,
    const unsigned short* __restrict__ W6hi, const unsigned short* __restrict__ W6lo,
    const unsigned short* __restrict__ Hhi, const unsigned short* __restrict__ Hlo,
    const float* __restrict__ bih, const float* __restrict__ bhh,
    const float* __restrict__ hprev, float* __restrict__ hnew,
    unsigned short* __restrict__ nhhi, unsigned short* __restrict__ nhlo,
    int* __restrict__ preds, int use_caption, int pred_col){
  char* gAh = smem;            // 12288
  char* gAl = smem + 12288;    // 12288
  char* gXh = smem + 24576;    // 4096
  char* gXl = smem + 28672;    // 4096
  char* gHh = smem + 32768;    // 4096
  char* gHl = smem + 36864;    // 4096
  float* comb = (float*)(smem + 40960);  // 2*768 floats
  int* tok = (int*)(smem + 47104);       // 32 ints

  int tid = threadIdx.x, w = tid >> 6, lane = tid & 63;
  int jbase = (blk & 31) * 16, bbase = (blk >> 5) * 32;
  int bsub = w & 1, grp = w >> 1;
  int b16 = lane & 15, q = lane >> 4;

  if (tid < 32){
    int t;
    if (use_caption) t = cap[bbase + tid];
    else {
      t = key_tok(slot_prev[bbase + tid]);
      if ((blk & 31) == 0) preds[(bbase + tid)*NT + pred_col] = t;
    }
    tok[tid] = t;
  }
  __syncthreads();

  float4v acc[3];
  #pragma unroll
  for (int g = 0; g < 3; g++) acc[g] = (float4v){0.f,0.f,0.f,0.f};

  for (int k0 = 0; k0 < NH; k0 += 64){
    #pragma unroll
    for (int i = 0; i < 6; i++){ // A: 24 issues
      int idx = w*6 + i;
      int arr = idx >= 12, t = arr ? (idx - 12) : idx;
      int a = t*8 + (lane >> 3);
      int glocal = a >> 4, jr = a & 15;
      int p = (lane & 7) ^ ((lane >> 3) & 7);
      const unsigned short* gs = (arr ? W6lo : W6hi)
          + (size_t)(glocal*512 + jbase + jr)*NH + k0 + p*8;
      async_load16(gs, (arr ? gAl : gAh) + t*1024);
    }
    #pragma unroll
    for (int i = 0; i < 2; i++){ // H: 8 issues
      int idx = w*2 + i;
      int arr = idx >> 2, t = idx & 3;
      int row = t*8 + (lane >> 3);
      int p = (lane & 7) ^ ((lane >> 3) & 7);
      const unsigned short* gs = (arr ? Hlo : Hhi)
          + (size_t)(bbase + row)*NH + k0 + p*8;
      async_load16(gs, (arr ? gHl : gHh) + t*1024);
    }
    { // X: emb gather fp32 -> split -> LDS (256 slots)
      int row = tid >> 3, sl = tid & 7;
      int p = sl ^ (row & 7);
      const float* gp = emb + (size_t)tok[row]*NH + k0 + p*8;
      float4 f0 = *(const float4*)gp, f1 = *(const float4*)(gp + 4);
      short8 hv, lv; unsigned short hh, ll;
      split2(f0.x,hh,ll); hv[0]=(short)hh; lv[0]=(short)ll;
      split2(f0.y,hh,ll); hv[1]=(short)hh; lv[1]=(short)ll;
      split2(f0.z,hh,ll); hv[2]=(short)hh; lv[2]=(short)ll;
      split2(f0.w,hh,ll); hv[3]=(short)hh; lv[3]=(short)ll;
      split2(f1.x,hh,ll); hv[4]=(short)hh; lv[4]=(short)ll;
      split2(f1.y,hh,ll); hv[5]=(short)hh; lv[5]=(short)ll;
      split2(f1.z,hh,ll); hv[6]=(short)hh; lv[6]=(short)ll;
      split2(f1.w,hh,ll); hv[7]=(short)hh; lv[7]=(short)ll;
      *(short8*)(gXh + row*128 + sl*16) = hv;
      *(short8*)(gXl + row*128 + sl*16) = lv;
    }
    __syncthreads();
    int rb = bsub*16 + b16;
    #pragma unroll
    for (int kh = 0; kh < 2; kh++){
      int pa = kh*4 + q;
      int boff = rb*128 + ((pa ^ (rb & 7))*16);
      short8 bh = grp ? *(const short8*)(gHh + boff) : *(const short8*)(gXh + boff);
      short8 bl = grp ? *(const short8*)(gHl + boff) : *(const short8*)(gXl + boff);
      #pragma unroll
      for (int gi = 0; gi < 3; gi++){
        int row = (grp*3 + gi)*16 + b16;
        int aoff = row*128 + ((pa ^ (row & 7))*16);
        short8 ah = *(const short8*)(gAh + aoff);
        short8 al = *(const short8*)(gAl + aoff);
        acc[gi] = __builtin_amdgcn_mfma_f32_16x16x32_bf16(ah, bh, acc[gi], 0,0,0);
        acc[gi] = __builtin_amdgcn_mfma_f32_16x16x32_bf16(ah, bl, acc[gi], 0,0,0);
        acc[gi] = __builtin_amdgcn_mfma_f32_16x16x32_bf16(al, bh, acc[gi], 0,0,0);
      }
    }
    __syncthreads();
  }

  if (grp == 1){
    #pragma unroll
    for (int gi = 0; gi < 3; gi++)
      #pragma unroll
      for (int reg = 0; reg < 4; reg++)
        comb[bsub*768 + gi*256 + b16*16 + q*4 + reg] = acc[gi][reg];
  }
  __syncthreads();
  if (grp == 0){
    int b = bbase + bsub*16 + b16;
    #pragma unroll
    for (int reg = 0; reg < 4; reg++){
      int jl = q*4 + reg;
      int j = jbase + jl;
      float hr = comb[bsub*768 + 0*256 + b16*16 + jl];
      float hz = comb[bsub*768 + 1*256 + b16*16 + jl];
      float hn = comb[bsub*768 + 2*256 + b16*16 + jl];
      float gr = acc[0][reg] + hr + bih[j] + bhh[j];
      float gz = acc[1][reg] + hz + bih[j+NH] + bhh[j+NH];
      float in_ = acc[2][reg] + bih[j+2*NH];
      float hn_ = hn + bhh[j+2*NH];
      float r = 1.f/(1.f + expf(-gr));
      float z = 1.f/(1.f + expf(-gz));
      float n = tanhf(in_ + r*hn_);
      float hp = hprev[(size_t)b*NH + j];
      float val = (1.f - z)*n + z*hp;
      hnew[(size_t)b*NH + j] = val;
      unsigned short sh, sl; split2(val, sh, sl);
      nhhi[(size_t)b*NH + j] = sh;
      nhlo[(size_t)b*NH + j] = sl;
    }
  }
}

// ---------------- phase: logits tile + atomic argmax (blk 0..501) ----------------
// smem use: exactly 65536 B (argmax scratch overlays sAh after the K-loop)
__device__ __forceinline__ void phase_pred(char* smem, int blk,
    const unsigned short* __restrict__ Hhi, const unsigned short* __restrict__ Hlo,
    const unsigned short* __restrict__ Whi, const unsigned short* __restrict__ Wlo,
    const float* __restrict__ bp,
    unsigned long long* __restrict__ slotp){
  char* sAh = smem;             // 16384
  char* sAl = smem + 16384;
  char* sBh = smem + 32768;
  char* sBl = smem + 49152;
  float* sval = (float*)smem;          // overlay on sAh (safe after K-loop)
  int*   sidx = (int*)(smem + 1024);

  int tid = threadIdx.x, w = tid >> 6, lane = tid & 63;
  int vbase = (blk >> 1)*128, bbase = (blk & 1)*128;
  int mhalf = w & 1, nhalf = w >> 1;
  char* mybuf = (w==0)?sAh:(w==1)?sAl:(w==2)?sBh:sBl;
  const unsigned short* gsrc = (w==0)?Whi:(w==1)?Wlo:(w==2)?Hhi:Hlo;
  int rowbase = (w < 2) ? vbase : bbase;
  int isA = (w < 2);
  int rl = lane >> 3, sl = lane & 7;
  int pq = sl ^ rl;
  float4v acc[4][4];
  #pragma unroll
  for (int mi=0;mi<4;mi++)
    #pragma unroll
    for (int ni=0;ni<4;ni++) acc[mi][ni] = (float4v){0.f,0.f,0.f,0.f};
  int q = lane >> 4, b16 = lane & 15;

  for (int k0 = 0; k0 < NH; k0 += 64){
    #pragma unroll
    for (int t = 0; t < 16; t++){
      int grow = rowbase + t*8 + rl;
      if (isA && grow > NV-1) grow = NV-1;
      const unsigned short* gp = gsrc + (size_t)grow*NH + k0 + pq*8;
      async_load16(gp, mybuf + t*1024);
    }
    __syncthreads();
    #pragma unroll
    for (int kh = 0; kh < 2; kh++){
      int pa = kh*4 + q;
      short8 ah[4], al[4], bh[4], bl[4];
      #pragma unroll
      for (int mi=0;mi<4;mi++){
        int r = mhalf*64 + mi*16 + b16;
        int off = r*128 + ((pa ^ (r & 7))*16);
        ah[mi] = *(const short8*)(sAh + off);
        al[mi] = *(const short8*)(sAl + off);
      }
      #pragma unroll
      for (int ni=0;ni<4;ni++){
        int r = nhalf*64 + ni*16 + b16;
        int off = r*128 + ((pa ^ (r & 7))*16);
        bh[ni] = *(const short8*)(sBh + off);
        bl[ni] = *(const short8*)(sBl + off);
      }
      #pragma unroll
      for (int mi=0;mi<4;mi++)
        #pragma unroll
        for (int ni=0;ni<4;ni++){
          acc[mi][ni] = __builtin_amdgcn_mfma_f32_16x16x32_bf16(ah[mi], bh[ni], acc[mi][ni], 0,0,0);
          acc[mi][ni] = __builtin_amdgcn_mfma_f32_16x16x32_bf16(ah[mi], bl[ni], acc[mi][ni], 0,0,0);
          acc[mi][ni] = __builtin_amdgcn_mfma_f32_16x16x32_bf16(al[mi], bh[ni], acc[mi][ni], 0,0,0);
        }
    }
    __syncthreads();
  }

  float bestv[4] = {-INFINITY,-INFINITY,-INFINITY,-INFINITY};
  int   besti[4] = {0x7fffffff,0x7fffffff,0x7fffffff,0x7fffffff};
  #pragma unroll
  for (int mi=0;mi<4;mi++){
    #pragma unroll
    for (int reg=0;reg<4;reg++){
      int v = vbase + mhalf*64 + mi*16 + q*4 + reg;
      if (v < NV){
        float bpv = bp[v];
        #pragma unroll
        for (int ni=0;ni<4;ni++){
          float cand = acc[mi][ni][reg] + bpv;
          if (cand > bestv[ni] || (cand == bestv[ni] && v < besti[ni])){
            bestv[ni] = cand; besti[ni] = v;
          }
        }
      }
    }
  }
  #pragma unroll
  for (int ni=0;ni<4;ni++){
    #pragma unroll
    for (int off=16; off<=32; off<<=1){
      float ov = __shfl_xor(bestv[ni], off);
      int   oi = __shfl_xor(besti[ni], off);
      if (ov > bestv[ni] || (ov == bestv[ni] && oi < besti[ni])){
        bestv[ni] = ov; besti[ni] = oi;
      }
    }
    if (lane < 16){
      sval[w*64 + ni*16 + b16] = bestv[ni];
      sidx[w*64 + ni*16 + b16] = besti[ni];
    }
  }
  __syncthreads();
  if (tid < 128){
    int nh = tid >> 6;
    int wA = nh*2, wB = nh*2 + 1;
    int so = tid & 63;
    float vA = sval[wA*64 + so], vB = sval[wB*64 + so];
    int   iA = sidx[wA*64 + so], iB = sidx[wB*64 + so];
    bool takeB = (vB > vA) || (vB == vA && iB < iA);
    atomicMax(slotp + bbase + tid, pack_key(takeB ? vB : vA, takeB ? iB : iA));
  }
}

// ---------------- the persistent cooperative kernel (65536 B LDS) ----------------
__global__ __launch_bounds__(256, 2) void k_mega(
    const int* cap, const float* img, const float* emb,
    const float* Wc, const float* bc,
    const float* wih, const float* whh, const float* bih, const float* bhh,
    const float* Wp, const float* bp,
    int* preds,
    float* h0b, float* h1b,
    unsigned short* Hhi0, unsigned short* Hlo0,
    unsigned short* Hhi1, unsigned short* Hlo1,
    unsigned short* Whi, unsigned short* Wlo,
    unsigned short* W6hi, unsigned short* W6lo,
    unsigned short* Wchi, unsigned short* Wclo,
    unsigned long long* slots, unsigned* barcnt)
{
  __shared__ __align__(16) char smem[65536];
  int tid = threadIdx.x, blk = blockIdx.x;
  unsigned bar_target = 0;

  // P0: seed preds col0 (slots pre-zeroed by host memset), split W6 + Wc
  if (blk == 0) preds[tid*NT] = cap[tid];
  for (size_t i = (size_t)blk*256 + tid; i < SP_SMALL; i += (size_t)NBLK*256)
    split_small_elem(i, wih, whh, Wc, W6hi, W6lo, Wchi, Wclo);
  gbar(barcnt, bar_target);

  // P1: h0 (blocks <128) || Wp split part A
  if (blk < 128)
    phase_h0(smem, blk, img, Wchi, Wclo, bc, h0b, Hhi0, Hlo0);
  else
    for (size_t i = (size_t)(blk-128)*256 + tid; i < WP_A; i += (size_t)374*256)
      split_elem(Wp, Whi, Wlo, i);
  gbar(barcnt, bar_target);

  // P2: gru step1 (blocks <256, caption tokens) || Wp split part B
  if (blk < 256)
    phase_gru(smem, blk, cap, slots, emb, W6hi, W6lo, Hhi0, Hlo0,
              bih, bhh, h0b, h1b, Hhi1, Hlo1, preds, 1, 0);
  else
    for (size_t i = WP_A + (size_t)(blk-256)*256 + tid; i < SP_P; i += (size_t)246*256)
      split_elem(Wp, Whi, Wlo, i);
  gbar(barcnt, bar_target);

  unsigned short* Hh[2] = {Hhi0, Hhi1};
  unsigned short* Hl[2] = {Hlo0, Hlo1};
  float* hb[2] = {h0b, h1b};

  for (int s = 1; s <= NT-1; s++){
    phase_pred(smem, blk, Hh[s&1], Hl[s&1], Whi, Wlo, bp, slots + (size_t)s*BATCH);
    gbar(barcnt, bar_target);
    if (s < NT-1){
      if (blk < 256)
        phase_gru(smem, blk, cap, slots + (size_t)s*BATCH, emb, W6hi, W6lo,
                  Hh[s&1], Hl[s&1], bih, bhh, hb[s&1], hb[(s+1)&1],
                  Hh[(s+1)&1], Hl[(s+1)&1], preds, 0, s);
      gbar(barcnt, bar_target);
    }
  }
  if (blk == 0)
    preds[tid*NT + (NT-1)] = key_tok(slots[(size_t)(NT-1)*BATCH + tid]);
}

// ================= multi-kernel MFMA path (round-4 proven; coop fallback) =========
__global__ void k_seed(const int* __restrict__ cap, int* __restrict__ preds){
  int b = threadIdx.x;
  preds[b*NT + 0] = cap[b];
}

__global__ __launch_bounds__(256) void k_split_w(const float* __restrict__ Wp,
    unsigned short* __restrict__ Whi, unsigned short* __restrict__ Wlo){
  size_t i = (size_t)blockIdx.x * 256 + threadIdx.x;
  if (i < SP_P) split_elem(Wp, Whi, Wlo, i);
}

__global__ __launch_bounds__(256) void k_split_small(
    const float* __restrict__ wih, const float* __restrict__ whh,
    const float* __restrict__ Wc,
    unsigned short* __restrict__ W6hi, unsigned short* __restrict__ W6lo,
    unsigned short* __restrict__ Wchi, unsigned short* __restrict__ Wclo){
  size_t i = (size_t)blockIdx.x * 256 + threadIdx.x;
  if (i < SP_SMALL) split_small_elem(i, wih, whh, Wc, W6hi, W6lo, Wchi, Wclo);
}

__global__ __launch_bounds__(256) void k_h0_mf(
    const float* __restrict__ img,
    const unsigned short* __restrict__ Wchi, const unsigned short* __restrict__ Wclo,
    const float* __restrict__ bc, float* __restrict__ h0,
    unsigned short* __restrict__ hhi, unsigned short* __restrict__ hlo){
  __shared__ __align__(16) char smem[20480];
  phase_h0(smem, blockIdx.x, img, Wchi, Wclo, bc, h0, hhi, hlo);
}

__global__ __launch_bounds__(256) void k_gru_mf(
    const int* __restrict__ cap, const unsigned long long* __restrict__ slot_prev,
    const float* __restrict__ emb,
    const unsigned short* __restrict__ W6hi, const unsigned short* __restrict__ W6lo,
    const unsigned short* __restrict__ Hhi, const unsigned short* __restrict__ Hlo,
    const float* __restrict__ bih, const float* __restrict__ bhh,
    const float* __restrict__ hprev, float* __restrict__ hnew,
    unsigned short* __restrict__ nhhi, unsigned short* __restrict__ nhlo,
    int* __restrict__ preds, int use_caption, int pred_col){
  __shared__ __align__(16) char smem[47232];
  phase_gru(smem, blockIdx.x, cap, slot_prev, emb, W6hi, W6lo, Hhi, Hlo,
            bih, bhh, hprev, hnew, nhhi, nhlo, preds, use_caption, pred_col);
}

__global__ __launch_bounds__(256) void k_pred_mf(
    const unsigned short* __restrict__ Hhi, const unsigned short* __restrict__ Hlo,
    const unsigned short* __restrict__ Whi, const unsigned short* __restrict__ Wlo,
    const float* __restrict__ bp, unsigned long long* __restrict__ slotp){
  __shared__ __align__(16) char smem[65536];
  phase_pred(smem, blockIdx.x, Hhi, Hlo, Whi, Wlo, bp, slotp);
}

__global__ void k_fin_slot(const unsigned long long* __restrict__ slot,
                           int* __restrict__ preds){
  int b = threadIdx.x;
  preds[b*NT + (NT-1)] = key_tok(slot[b]);
}

extern "C" void kernel_launch(void* const* d_in, const int* in_sizes, int n_in,
                              void* d_out, int out_size, void* d_ws, size_t ws_size,
                              hipStream_t stream){
  const int*   cap = (const int*)d_in[0];
  const float* img = (const float*)d_in[1];
  const float* emb = (const float*)d_in[2];
  const float* Wc  = (const float*)d_in[3];
  const float* bc  = (const float*)d_in[4];
  const float* wih = (const float*)d_in[5];
  const float* whh = (const float*)d_in[6];
  const float* bih = (const float*)d_in[7];
  const float* bhh = (const float*)d_in[8];
  const float* Wp  = (const float*)d_in[9];
  const float* bp  = (const float*)d_in[10];
  int* preds = (int*)d_out;

  char* p = (char*)d_ws;
  float* h0b = (float*)p;                   p += (size_t)BATCH*NH*4;
  float* h1b = (float*)p;                   p += (size_t)BATCH*NH*4;
  unsigned short* Hhi0 = (unsigned short*)p; p += (size_t)BATCH*NH*2;
  unsigned short* Hlo0 = (unsigned short*)p; p += (size_t)BATCH*NH*2;
  unsigned short* Hhi1 = (unsigned short*)p; p += (size_t)BATCH*NH*2;
  unsigned short* Hlo1 = (unsigned short*)p; p += (size_t)BATCH*NH*2;
  unsigned short* Whi = (unsigned short*)p;  p += (size_t)NV*NH*2;
  unsigned short* Wlo = (unsigned short*)p;  p += (size_t)NV*NH*2;
  unsigned short* W6hi = (unsigned short*)p; p += (size_t)3072*NH*2;
  unsigned short* W6lo = (unsigned short*)p; p += (size_t)3072*NH*2;
  unsigned short* Wchi = (unsigned short*)p; p += (size_t)NH*NCOND*2;
  unsigned short* Wclo = (unsigned short*)p; p += (size_t)NH*NCOND*2;
  unsigned long long* slots = (unsigned long long*)p; p += (size_t)NT*BATCH*8;
  unsigned* barcnt = (unsigned*)p;           p += 64;

  hipMemsetAsync(barcnt, 0, 4, stream);
  hipMemsetAsync(slots, 0, (size_t)NT*BATCH*8, stream);

  void* args[] = {
    (void*)&cap, (void*)&img, (void*)&emb, (void*)&Wc, (void*)&bc,
    (void*)&wih, (void*)&whh, (void*)&bih, (void*)&bhh, (void*)&Wp, (void*)&bp,
    (void*)&preds, (void*)&h0b, (void*)&h1b,
    (void*)&Hhi0, (void*)&Hlo0, (void*)&Hhi1, (void*)&Hlo1,
    (void*)&Whi, (void*)&Wlo, (void*)&W6hi, (void*)&W6lo,
    (void*)&Wchi, (void*)&Wclo, (void*)&slots, (void*)&barcnt
  };
  hipError_t err = hipLaunchCooperativeKernel((const void*)k_mega, dim3(NBLK),
                                              dim3(256), args, 0, stream);
  if (err != hipSuccess){
    // proven round-4 multi-kernel schedule, same phase code
    k_seed<<<1, 256, 0, stream>>>(cap, preds);
    k_split_small<<<dim3(SP_SMALL/256), 256, 0, stream>>>(wih, whh, Wc,
                                                          W6hi, W6lo, Wchi, Wclo);
    k_h0_mf<<<dim3(128), 256, 0, stream>>>(img, Wchi, Wclo, bc, h0b, Hhi0, Hlo0);
    unsigned short* Hh[2] = {Hhi0, Hhi1};
    unsigned short* Hl[2] = {Hlo0, Hlo1};
    float* hb[2] = {h0b, h1b};
    k_gru_mf<<<dim3(256), 256, 0, stream>>>(cap, slots, emb, W6hi, W6lo,
        Hh[0], Hl[0], bih, bhh, hb[0], hb[1], Hh[1], Hl[1], preds, 1, 0);
    k_split_w<<<dim3(SP_P/256), 256, 0, stream>>>(Wp, Whi, Wlo);
    k_pred_mf<<<dim3(NBLK), 256, 0, stream>>>(Hh[1], Hl[1], Whi, Wlo, bp,
                                              slots + 1*BATCH);
    for (int s = 2; s <= NT-1; s++){
      int pi = (s-1)&1, ci = s&1;
      k_gru_mf<<<dim3(256), 256, 0, stream>>>(cap, slots + (size_t)(s-1)*BATCH,
          emb, W6hi, W6lo, Hh[pi], Hl[pi], bih, bhh,
          hb[pi], hb[ci], Hh[ci], Hl[ci], preds, 0, s-1);
      k_pred_mf<<<dim3(NBLK), 256, 0, stream>>>(Hh[ci], Hl[ci], Whi, Wlo, bp,
                                                slots + (size_t)s*BATCH);
    }
    k_fin_slot<<<1, 256, 0, stream>>>(slots + (size_t)(NT-1)*BATCH, preds);
  }
}